// Round 1
// baseline (2510.953 us; speedup 1.0000x reference)
//
#include <hip/hip_runtime.h>

// Problem constants
#define B_ 8
#define V_ 10000
#define E_ 160000
#define DIN 128
#define DOUT 128
#define M_ (B_*V_)          // 80000 rows
#define NINV (1.0f/80000.0f)
#define BN_EPS 1e-5f

// Workspace layout (floats):
//   A      @ 0          : M_*128 = 10,240,000   (scatter accumulator)
//   s      @ 10,240,000 : M_     = 80,000       (edge_attr scatter)
//   gsum   @ 10,320,000 : 128
//   gsumsq @ 10,320,128 : 128
//   scale  @ 10,320,256 : 128
//   shift  @ 10,320,384 : 128
#define WS_A      0
#define WS_S      10240000
#define WS_SUM    10320000
#define WS_SUMSQ  10320128
#define WS_SCALE  10320256
#define WS_SHIFT  10320384
#define WS_ZERO_FLOATS 10320256   // zero A, s, gsum, gsumsq

// ---------------------------------------------------------------------------
// Kernel 1: scatter-add  A[b,dst,:] += X[b,src,:];  s[b,dst] += edge_attr[b,e]
// One 32-thread group per (b,edge); each thread handles 4 contiguous floats.
// ---------------------------------------------------------------------------
__global__ __launch_bounds__(256) void scatter_kernel(
    const float* __restrict__ X, const float* __restrict__ EA,
    const int* __restrict__ EI, float* __restrict__ A, float* __restrict__ S)
{
    int g = blockIdx.x * 256 + threadIdx.x;
    int slot = g >> 5;          // (b,e) pair index, < B_*E_
    int q = g & 31;             // which float4 of the 128-dim row
    int b = slot / E_;
    int e = slot - b * E_;
    int src = EI[2 * e];
    int dst = EI[2 * e + 1];
    const float4 v = *(const float4*)(X + ((size_t)b * V_ + src) * DIN + q * 4);
    float* d = A + ((size_t)b * V_ + dst) * DIN + q * 4;
    atomicAdd(d + 0, v.x);
    atomicAdd(d + 1, v.y);
    atomicAdd(d + 2, v.z);
    atomicAdd(d + 3, v.w);
    if (q == 0) {
        atomicAdd(S + (size_t)b * V_ + dst, EA[(size_t)b * E_ + e]);
    }
}

// ---------------------------------------------------------------------------
// Kernel 2: fused GEMM  H = [X|A] @ [W_self|W_node]^T + b_self + s*w_edge
// M=80000, N=128, K=256. Tile: 64 rows x 128 outs per 256-thread block;
// micro-tile 8 rows x 4 outs per thread. K chunked by 64 through LDS.
// Also accumulates per-channel sum / sumsq for the batchnorm.
// ---------------------------------------------------------------------------
__global__ __launch_bounds__(256) void gemm_stats_kernel(
    const float* __restrict__ X, const float* __restrict__ A,
    const float* __restrict__ S,
    const float* __restrict__ Wself, const float* __restrict__ Wnode,
    const float* __restrict__ bself, const float* __restrict__ wedge,
    float* __restrict__ H, float* __restrict__ gsum, float* __restrict__ gsumsq)
{
    __shared__ float u_tile[64][68];    // [row][k] padded
    __shared__ float w_tile[64][132];   // [k][o]  padded (transposed weights)
    __shared__ float cs[128];
    __shared__ float css[128];

    const int t = threadIdx.x;
    const int row0 = blockIdx.x * 64;
    const int o0 = (t & 31) * 4;        // 4 output channels
    const int r0 = (t >> 5) * 8;        // 8 rows

    float acc[8][4];
#pragma unroll
    for (int r = 0; r < 8; ++r)
#pragma unroll
        for (int j = 0; j < 4; ++j) acc[r][j] = 0.0f;

    if (t < 128) { cs[t] = 0.0f; css[t] = 0.0f; }

    for (int kc = 0; kc < 4; ++kc) {
        const float* usrc = (kc < 2) ? (X + kc * 64) : (A + (kc - 2) * 64);
        const float* wsrc = (kc < 2) ? (Wself + kc * 64) : (Wnode + (kc - 2) * 64);

        // stage U: 64 rows x 64 k  (each row-chunk is 256B, read by 16 lanes)
#pragma unroll
        for (int i = 0; i < 4; ++i) {
            int idx4 = t + i * 256;
            int r = idx4 >> 4;
            int j4 = idx4 & 15;
            float4 v = *(const float4*)(usrc + (size_t)(row0 + r) * DIN + j4 * 4);
            *(float4*)&u_tile[r][j4 * 4] = v;
        }
        // stage W transposed: 128 o x 64 k -> w_tile[k][o]
#pragma unroll
        for (int i = 0; i < 8; ++i) {
            int idx4 = t + i * 256;
            int o = idx4 >> 4;
            int j4 = idx4 & 15;
            float4 v = *(const float4*)(wsrc + (size_t)o * DIN + j4 * 4);
            w_tile[j4 * 4 + 0][o] = v.x;
            w_tile[j4 * 4 + 1][o] = v.y;
            w_tile[j4 * 4 + 2][o] = v.z;
            w_tile[j4 * 4 + 3][o] = v.w;
        }
        __syncthreads();

#pragma unroll
        for (int k4 = 0; k4 < 16; ++k4) {
            float4 wf0 = *(float4*)&w_tile[4 * k4 + 0][o0];
            float4 wf1 = *(float4*)&w_tile[4 * k4 + 1][o0];
            float4 wf2 = *(float4*)&w_tile[4 * k4 + 2][o0];
            float4 wf3 = *(float4*)&w_tile[4 * k4 + 3][o0];
#pragma unroll
            for (int r = 0; r < 8; ++r) {
                float4 uf = *(float4*)&u_tile[r0 + r][4 * k4];
                acc[r][0] += uf.x * wf0.x + uf.y * wf1.x + uf.z * wf2.x + uf.w * wf3.x;
                acc[r][1] += uf.x * wf0.y + uf.y * wf1.y + uf.z * wf2.y + uf.w * wf3.y;
                acc[r][2] += uf.x * wf0.z + uf.y * wf1.z + uf.z * wf2.z + uf.w * wf3.z;
                acc[r][3] += uf.x * wf0.w + uf.y * wf1.w + uf.z * wf2.w + uf.w * wf3.w;
            }
        }
        __syncthreads();
    }

    // epilogue: add bias + s*w_edge, store H, accumulate channel stats
    const float4 bs = *(const float4*)(bself + o0);
    const float4 we = *(const float4*)(wedge + o0);
    float psum[4] = {0, 0, 0, 0};
    float psq[4] = {0, 0, 0, 0};
#pragma unroll
    for (int r = 0; r < 8; ++r) {
        int row = row0 + r0 + r;
        float sv = S[row];
        float4 h;
        h.x = acc[r][0] + bs.x + sv * we.x;
        h.y = acc[r][1] + bs.y + sv * we.y;
        h.z = acc[r][2] + bs.z + sv * we.z;
        h.w = acc[r][3] + bs.w + sv * we.w;
        *(float4*)(H + (size_t)row * DOUT + o0) = h;
        psum[0] += h.x; psum[1] += h.y; psum[2] += h.z; psum[3] += h.w;
        psq[0] += h.x * h.x; psq[1] += h.y * h.y;
        psq[2] += h.z * h.z; psq[3] += h.w * h.w;
    }
#pragma unroll
    for (int j = 0; j < 4; ++j) {
        atomicAdd(&cs[o0 + j], psum[j]);
        atomicAdd(&css[o0 + j], psq[j]);
    }
    __syncthreads();
    if (t < 128) {
        atomicAdd(&gsum[t], cs[t]);
        atomicAdd(&gsumsq[t], css[t]);
    }
}

// ---------------------------------------------------------------------------
// Kernel 3: finalize batchnorm stats -> scale/shift per channel
// ---------------------------------------------------------------------------
__global__ void finalize_kernel(
    const float* __restrict__ gsum, const float* __restrict__ gsumsq,
    const float* __restrict__ gamma, const float* __restrict__ beta,
    float* __restrict__ scale, float* __restrict__ shift)
{
    int o = threadIdx.x;  // 128 threads
    float mean = gsum[o] * NINV;
    float var = gsumsq[o] * NINV - mean * mean;
    float rstd = rsqrtf(var + BN_EPS);
    float sc = gamma[o] * rstd;
    scale[o] = sc;
    shift[o] = beta[o] - mean * sc;
}

// ---------------------------------------------------------------------------
// Kernel 4: normalize + ReLU in place on d_out
// ---------------------------------------------------------------------------
__global__ __launch_bounds__(256) void norm_relu_kernel(
    float* __restrict__ H, const float* __restrict__ scale,
    const float* __restrict__ shift)
{
    int idx = blockIdx.x * 256 + threadIdx.x;   // over M_*128/4 float4s
    int o4 = (idx & 31) * 4;
    float4 h = ((const float4*)H)[idx];
    float4 sc = *(const float4*)(scale + o4);
    float4 sh = *(const float4*)(shift + o4);
    h.x = fmaxf(h.x * sc.x + sh.x, 0.0f);
    h.y = fmaxf(h.y * sc.y + sh.y, 0.0f);
    h.z = fmaxf(h.z * sc.z + sh.z, 0.0f);
    h.w = fmaxf(h.w * sc.w + sh.w, 0.0f);
    ((float4*)H)[idx] = h;
}

// ---------------------------------------------------------------------------
extern "C" void kernel_launch(void* const* d_in, const int* in_sizes, int n_in,
                              void* d_out, int out_size, void* d_ws, size_t ws_size,
                              hipStream_t stream)
{
    const float* X      = (const float*)d_in[0];
    const float* EA     = (const float*)d_in[1];  // edge_attr
    const float* Wnode  = (const float*)d_in[2];
    const float* Wedge  = (const float*)d_in[3];
    const float* Wself  = (const float*)d_in[4];
    const float* bself  = (const float*)d_in[5];
    const float* gamma  = (const float*)d_in[6];
    const float* beta   = (const float*)d_in[7];
    const int*   EI     = (const int*)d_in[8];

    float* ws     = (float*)d_ws;
    float* A      = ws + WS_A;
    float* S      = ws + WS_S;
    float* gsum   = ws + WS_SUM;
    float* gsumsq = ws + WS_SUMSQ;
    float* scale  = ws + WS_SCALE;
    float* shift  = ws + WS_SHIFT;
    float* H      = (float*)d_out;

    // zero the accumulators (ws is re-poisoned to 0xAA before every call)
    hipMemsetAsync(ws, 0, (size_t)WS_ZERO_FLOATS * sizeof(float), stream);

    // 1) scatter-add of X rows and edge_attr by dst
    {
        int total_threads = B_ * E_ * 32;     // 32 threads per (b,e)
        int blocks = total_threads / 256;     // 160000
        scatter_kernel<<<blocks, 256, 0, stream>>>(X, EA, EI, A, S);
    }
    // 2) fused GEMM + stats
    gemm_stats_kernel<<<M_ / 64, 256, 0, stream>>>(X, A, S, Wself, Wnode,
                                                   bself, Wedge, H, gsum, gsumsq);
    // 3) stats -> scale/shift
    finalize_kernel<<<1, 128, 0, stream>>>(gsum, gsumsq, gamma, beta, scale, shift);
    // 4) normalize + relu in place
    norm_relu_kernel<<<(M_ * DOUT / 4) / 256, 256, 0, stream>>>(H, scale, shift);
}

// Round 2
// 529.407 us; speedup vs baseline: 4.7430x; 4.7430x over previous
//
#include <hip/hip_runtime.h>

// Problem constants
#define B_ 8
#define V_ 10000
#define E_ 160000
#define DIN 128
#define DOUT 128
#define M_ (B_*V_)          // 80000 rows
#define NINV (1.0f/80000.0f)
#define BN_EPS 1e-5f

// Workspace layout (4-byte units):
//   counts   @ 0        : V_      (zeroed)
//   gsum     @ 10000    : 128     (zeroed)
//   gsumsq   @ 10128    : 128     (zeroed)
//   scale    @ 10256    : 128
//   shift    @ 10384    : 128
//   row_ptr  @ 10512    : V_+1
//   cursor   @ 20513    : V_
//   ssrc     @ 30513    : E_
//   seid     @ 190513   : E_
//   S        @ 350513   : M_
//   A        @ 430513   : M_*128
#define WS_COUNTS  0
#define WS_SUM     10000
#define WS_SUMSQ   10128
#define WS_SCALE   10256
#define WS_SHIFT   10384
#define WS_ROWPTR  10512
#define WS_CURSOR  20513
#define WS_SSRC    30513
#define WS_SEID    190513
#define WS_S       350513
#define WS_A       430513
#define WS_ZERO_UNITS 10256   // counts + gsum + gsumsq

// ---------------------------------------------------------------------------
// 1) histogram of dst
// ---------------------------------------------------------------------------
__global__ __launch_bounds__(256) void hist_kernel(
    const int* __restrict__ EI, int* __restrict__ counts)
{
    int e = blockIdx.x * 256 + threadIdx.x;
    if (e < E_) atomicAdd(&counts[EI[2 * e + 1]], 1);
}

// ---------------------------------------------------------------------------
// 2) exclusive prefix sum over counts -> row_ptr, cursor (single block)
// ---------------------------------------------------------------------------
__global__ __launch_bounds__(256) void scan_kernel(
    const int* __restrict__ counts, int* __restrict__ row_ptr,
    int* __restrict__ cursor)
{
    __shared__ int psum[256];
    const int t = threadIdx.x;
    const int base = t * 40;              // 256*40 = 10240 >= V_
    int local[40];
    int s = 0;
#pragma unroll
    for (int i = 0; i < 40; ++i) {
        int idx = base + i;
        int c = (idx < V_) ? counts[idx] : 0;
        local[i] = s;
        s += c;
    }
    psum[t] = s;
    __syncthreads();
    for (int off = 1; off < 256; off <<= 1) {
        int v = (t >= off) ? psum[t - off] : 0;
        __syncthreads();
        psum[t] += v;
        __syncthreads();
    }
    int excl = (t == 0) ? 0 : psum[t - 1];
#pragma unroll
    for (int i = 0; i < 40; ++i) {
        int idx = base + i;
        if (idx < V_) {
            int rp = excl + local[i];
            row_ptr[idx] = rp;
            cursor[idx] = rp;
        }
    }
    if (t == 255) row_ptr[V_] = psum[255];
}

// ---------------------------------------------------------------------------
// 3) scatter edges into dst-sorted buckets
// ---------------------------------------------------------------------------
__global__ __launch_bounds__(256) void bucket_kernel(
    const int* __restrict__ EI, int* __restrict__ cursor,
    int* __restrict__ ssrc, int* __restrict__ seid)
{
    int e = blockIdx.x * 256 + threadIdx.x;
    if (e < E_) {
        int src = EI[2 * e];
        int dst = EI[2 * e + 1];
        int p = atomicAdd(&cursor[dst], 1);
        ssrc[p] = src;
        seid[p] = e;
    }
}

// ---------------------------------------------------------------------------
// 4) gather-reduce: A[b,d,:] = sum_{e: dst=d} X[b,src(e),:]; S[b,d] = sum ea
//    one wave per (b,d); 64 lanes x float2 = 128 floats
// ---------------------------------------------------------------------------
__global__ __launch_bounds__(256) void gather_kernel(
    const float* __restrict__ X, const float* __restrict__ EA,
    const int* __restrict__ row_ptr, const int* __restrict__ ssrc,
    const int* __restrict__ seid, float* __restrict__ A, float* __restrict__ S)
{
    int wave = (blockIdx.x * 256 + threadIdx.x) >> 6;   // 0 .. M_-1
    int lane = threadIdx.x & 63;
    int b = wave / V_;
    int d = wave - b * V_;
    int k0 = row_ptr[d];
    int k1 = row_ptr[d + 1];
    const float* Xb = X + (size_t)b * V_ * DIN + lane * 2;
    float2 acc = make_float2(0.0f, 0.0f);
    float sacc = 0.0f;
    for (int k = k0; k < k1; ++k) {
        int src = ssrc[k];
        float2 v = *(const float2*)(Xb + (size_t)src * DIN);
        acc.x += v.x;
        acc.y += v.y;
        if (lane == 0) sacc += EA[(size_t)b * E_ + seid[k]];
    }
    *(float2*)(A + (size_t)wave * DIN + lane * 2) = acc;
    if (lane == 0) S[wave] = sacc;
}

// ---------------------------------------------------------------------------
// 5) fused GEMM  H = [X|A] @ [W_self|W_node]^T + b_self + s*w_edge  (+stats)
// ---------------------------------------------------------------------------
__global__ __launch_bounds__(256) void gemm_stats_kernel(
    const float* __restrict__ X, const float* __restrict__ A,
    const float* __restrict__ S,
    const float* __restrict__ Wself, const float* __restrict__ Wnode,
    const float* __restrict__ bself, const float* __restrict__ wedge,
    float* __restrict__ H, float* __restrict__ gsum, float* __restrict__ gsumsq)
{
    __shared__ float u_tile[64][68];    // [row][k] padded
    __shared__ float w_tile[64][132];   // [k][o]  padded (transposed weights)
    __shared__ float cs[128];
    __shared__ float css[128];

    const int t = threadIdx.x;
    const int row0 = blockIdx.x * 64;
    const int o0 = (t & 31) * 4;        // 4 output channels
    const int r0 = (t >> 5) * 8;        // 8 rows

    float acc[8][4];
#pragma unroll
    for (int r = 0; r < 8; ++r)
#pragma unroll
        for (int j = 0; j < 4; ++j) acc[r][j] = 0.0f;

    if (t < 128) { cs[t] = 0.0f; css[t] = 0.0f; }

    for (int kc = 0; kc < 4; ++kc) {
        const float* usrc = (kc < 2) ? (X + kc * 64) : (A + (kc - 2) * 64);
        const float* wsrc = (kc < 2) ? (Wself + kc * 64) : (Wnode + (kc - 2) * 64);

#pragma unroll
        for (int i = 0; i < 4; ++i) {
            int idx4 = t + i * 256;
            int r = idx4 >> 4;
            int j4 = idx4 & 15;
            float4 v = *(const float4*)(usrc + (size_t)(row0 + r) * DIN + j4 * 4);
            *(float4*)&u_tile[r][j4 * 4] = v;
        }
#pragma unroll
        for (int i = 0; i < 8; ++i) {
            int idx4 = t + i * 256;
            int o = idx4 >> 4;
            int j4 = idx4 & 15;
            float4 v = *(const float4*)(wsrc + (size_t)o * DIN + j4 * 4);
            w_tile[j4 * 4 + 0][o] = v.x;
            w_tile[j4 * 4 + 1][o] = v.y;
            w_tile[j4 * 4 + 2][o] = v.z;
            w_tile[j4 * 4 + 3][o] = v.w;
        }
        __syncthreads();

#pragma unroll
        for (int k4 = 0; k4 < 16; ++k4) {
            float4 wf0 = *(float4*)&w_tile[4 * k4 + 0][o0];
            float4 wf1 = *(float4*)&w_tile[4 * k4 + 1][o0];
            float4 wf2 = *(float4*)&w_tile[4 * k4 + 2][o0];
            float4 wf3 = *(float4*)&w_tile[4 * k4 + 3][o0];
#pragma unroll
            for (int r = 0; r < 8; ++r) {
                float4 uf = *(float4*)&u_tile[r0 + r][4 * k4];
                acc[r][0] += uf.x * wf0.x + uf.y * wf1.x + uf.z * wf2.x + uf.w * wf3.x;
                acc[r][1] += uf.x * wf0.y + uf.y * wf1.y + uf.z * wf2.y + uf.w * wf3.y;
                acc[r][2] += uf.x * wf0.z + uf.y * wf1.z + uf.z * wf2.z + uf.w * wf3.z;
                acc[r][3] += uf.x * wf0.w + uf.y * wf1.w + uf.z * wf2.w + uf.w * wf3.w;
            }
        }
        __syncthreads();
    }

    const float4 bs = *(const float4*)(bself + o0);
    const float4 we = *(const float4*)(wedge + o0);
    float psum[4] = {0, 0, 0, 0};
    float psq[4] = {0, 0, 0, 0};
#pragma unroll
    for (int r = 0; r < 8; ++r) {
        int row = row0 + r0 + r;
        float sv = S[row];
        float4 h;
        h.x = acc[r][0] + bs.x + sv * we.x;
        h.y = acc[r][1] + bs.y + sv * we.y;
        h.z = acc[r][2] + bs.z + sv * we.z;
        h.w = acc[r][3] + bs.w + sv * we.w;
        *(float4*)(H + (size_t)row * DOUT + o0) = h;
        psum[0] += h.x; psum[1] += h.y; psum[2] += h.z; psum[3] += h.w;
        psq[0] += h.x * h.x; psq[1] += h.y * h.y;
        psq[2] += h.z * h.z; psq[3] += h.w * h.w;
    }
#pragma unroll
    for (int j = 0; j < 4; ++j) {
        atomicAdd(&cs[o0 + j], psum[j]);
        atomicAdd(&css[o0 + j], psq[j]);
    }
    __syncthreads();
    if (t < 128) {
        atomicAdd(&gsum[t], cs[t]);
        atomicAdd(&gsumsq[t], css[t]);
    }
}

// ---------------------------------------------------------------------------
// 6) finalize stats -> scale/shift
// ---------------------------------------------------------------------------
__global__ void finalize_kernel(
    const float* __restrict__ gsum, const float* __restrict__ gsumsq,
    const float* __restrict__ gamma, const float* __restrict__ beta,
    float* __restrict__ scale, float* __restrict__ shift)
{
    int o = threadIdx.x;  // 128 threads
    float mean = gsum[o] * NINV;
    float var = gsumsq[o] * NINV - mean * mean;
    float rstd = rsqrtf(var + BN_EPS);
    float sc = gamma[o] * rstd;
    scale[o] = sc;
    shift[o] = beta[o] - mean * sc;
}

// ---------------------------------------------------------------------------
// 7) normalize + ReLU in place on d_out
// ---------------------------------------------------------------------------
__global__ __launch_bounds__(256) void norm_relu_kernel(
    float* __restrict__ H, const float* __restrict__ scale,
    const float* __restrict__ shift)
{
    int idx = blockIdx.x * 256 + threadIdx.x;   // over M_*128/4 float4s
    int o4 = (idx & 31) * 4;
    float4 h = ((const float4*)H)[idx];
    float4 sc = *(const float4*)(scale + o4);
    float4 sh = *(const float4*)(shift + o4);
    h.x = fmaxf(h.x * sc.x + sh.x, 0.0f);
    h.y = fmaxf(h.y * sc.y + sh.y, 0.0f);
    h.z = fmaxf(h.z * sc.z + sh.z, 0.0f);
    h.w = fmaxf(h.w * sc.w + sh.w, 0.0f);
    ((float4*)H)[idx] = h;
}

// ---------------------------------------------------------------------------
extern "C" void kernel_launch(void* const* d_in, const int* in_sizes, int n_in,
                              void* d_out, int out_size, void* d_ws, size_t ws_size,
                              hipStream_t stream)
{
    const float* X      = (const float*)d_in[0];
    const float* EA     = (const float*)d_in[1];
    const float* Wnode  = (const float*)d_in[2];
    const float* Wedge  = (const float*)d_in[3];
    const float* Wself  = (const float*)d_in[4];
    const float* bself  = (const float*)d_in[5];
    const float* gamma  = (const float*)d_in[6];
    const float* beta   = (const float*)d_in[7];
    const int*   EI     = (const int*)d_in[8];

    int*   wsI    = (int*)d_ws;
    float* wsF    = (float*)d_ws;
    int*   counts = wsI + WS_COUNTS;
    float* gsum   = wsF + WS_SUM;
    float* gsumsq = wsF + WS_SUMSQ;
    float* scale  = wsF + WS_SCALE;
    float* shift  = wsF + WS_SHIFT;
    int*   rowptr = wsI + WS_ROWPTR;
    int*   cursor = wsI + WS_CURSOR;
    int*   ssrc   = wsI + WS_SSRC;
    int*   seid   = wsI + WS_SEID;
    float* S      = wsF + WS_S;
    float* A      = wsF + WS_A;
    float* H      = (float*)d_out;

    // zero counts + gsum + gsumsq (tiny)
    hipMemsetAsync(d_ws, 0, (size_t)WS_ZERO_UNITS * 4, stream);

    // CSR build (edge list is batch-independent)
    hist_kernel<<<(E_ + 255) / 256, 256, 0, stream>>>(EI, counts);
    scan_kernel<<<1, 256, 0, stream>>>(counts, rowptr, cursor);
    bucket_kernel<<<(E_ + 255) / 256, 256, 0, stream>>>(EI, cursor, ssrc, seid);

    // gather-reduce: one wave per (b,d), 4 waves per block
    gather_kernel<<<M_ / 4, 256, 0, stream>>>(X, EA, rowptr, ssrc, seid, A, S);

    // fused GEMM + stats
    gemm_stats_kernel<<<M_ / 64, 256, 0, stream>>>(X, A, S, Wself, Wnode,
                                                   bself, Wedge, H, gsum, gsumsq);
    finalize_kernel<<<1, 128, 0, stream>>>(gsum, gsumsq, gamma, beta, scale, shift);
    norm_relu_kernel<<<(M_ * DOUT / 4) / 256, 256, 0, stream>>>(H, scale, shift);
}

// Round 3
// 307.008 us; speedup vs baseline: 8.1788x; 1.7244x over previous
//
#include <hip/hip_runtime.h>

// Problem constants
#define B_ 8
#define V_ 10000
#define E_ 160000
#define DIN 128
#define DOUT 128
#define M_ (B_*V_)          // 80000 rows
#define NINV (1.0f/80000.0f)
#define BN_EPS 1e-5f

// Workspace layout (4-byte units):
#define WS_COUNTS  0            // V_            (zeroed)
#define WS_SUM     10000        // 128           (zeroed)
#define WS_SUMSQ   10128        // 128           (zeroed)
#define WS_SCALE   10256        // 128
#define WS_SHIFT   10384        // 128
#define WS_ROWPTR  10512        // V_+1
#define WS_CURSOR  20513        // V_
#define WS_SSRC    30513        // E_
#define WS_SEID    190513       // E_
#define WS_S       350513       // M_
#define WS_WBF     430516       // 16384 units  = 32768 bf16  (16B aligned)
#define WS_XBF     446900       // 5,120,000 units = 10.24M bf16 (16B aligned)
#define WS_ABF     5566900      // 5,120,000 units (16B aligned)
#define WS_ZERO_UNITS 10256     // counts + gsum + gsumsq

typedef __attribute__((ext_vector_type(8))) short short8;
typedef __attribute__((ext_vector_type(4))) float f32x4;

__device__ inline unsigned short f2bf(float x) {
    union { float f; unsigned u; } v; v.f = x;
    unsigned r = v.u + 0x7FFFu + ((v.u >> 16) & 1u);   // RNE
    return (unsigned short)(r >> 16);
}

// ---------------------------------------------------------------------------
// 1) histogram of dst
// ---------------------------------------------------------------------------
__global__ __launch_bounds__(256) void hist_kernel(
    const int* __restrict__ EI, int* __restrict__ counts)
{
    int e = blockIdx.x * 256 + threadIdx.x;
    if (e < E_) atomicAdd(&counts[EI[2 * e + 1]], 1);
}

// ---------------------------------------------------------------------------
// 2) exclusive prefix sum over counts -> row_ptr, cursor (single block)
// ---------------------------------------------------------------------------
__global__ __launch_bounds__(256) void scan_kernel(
    const int* __restrict__ counts, int* __restrict__ row_ptr,
    int* __restrict__ cursor)
{
    __shared__ int psum[256];
    const int t = threadIdx.x;
    const int base = t * 40;              // 256*40 = 10240 >= V_
    int local[40];
    int s = 0;
#pragma unroll
    for (int i = 0; i < 40; ++i) {
        int idx = base + i;
        int c = (idx < V_) ? counts[idx] : 0;
        local[i] = s;
        s += c;
    }
    psum[t] = s;
    __syncthreads();
    for (int off = 1; off < 256; off <<= 1) {
        int v = (t >= off) ? psum[t - off] : 0;
        __syncthreads();
        psum[t] += v;
        __syncthreads();
    }
    int excl = (t == 0) ? 0 : psum[t - 1];
#pragma unroll
    for (int i = 0; i < 40; ++i) {
        int idx = base + i;
        if (idx < V_) {
            int rp = excl + local[i];
            row_ptr[idx] = rp;
            cursor[idx] = rp;
        }
    }
    if (t == 255) row_ptr[V_] = psum[255];
}

// ---------------------------------------------------------------------------
// 3) scatter edges into dst-sorted buckets
// ---------------------------------------------------------------------------
__global__ __launch_bounds__(256) void bucket_kernel(
    const int* __restrict__ EI, int* __restrict__ cursor,
    int* __restrict__ ssrc, int* __restrict__ seid)
{
    int e = blockIdx.x * 256 + threadIdx.x;
    if (e < E_) {
        int src = EI[2 * e];
        int dst = EI[2 * e + 1];
        int p = atomicAdd(&cursor[dst], 1);
        ssrc[p] = src;
        seid[p] = e;
    }
}

// ---------------------------------------------------------------------------
// 4) X -> bf16 prepass
// ---------------------------------------------------------------------------
__global__ __launch_bounds__(256) void xcvt_kernel(
    const float* __restrict__ X, unsigned short* __restrict__ Xbf)
{
    int idx = blockIdx.x * 256 + threadIdx.x;      // over M_*DIN/4
    float4 v = ((const float4*)X)[idx];
    ushort4 o;
    o.x = f2bf(v.x); o.y = f2bf(v.y); o.z = f2bf(v.z); o.w = f2bf(v.w);
    ((ushort4*)Xbf)[idx] = o;
}

// ---------------------------------------------------------------------------
// 5) pack [W_self | W_node] -> Wbf[o][256] bf16
// ---------------------------------------------------------------------------
__global__ __launch_bounds__(256) void wcvt_kernel(
    const float* __restrict__ Wself, const float* __restrict__ Wnode,
    unsigned short* __restrict__ Wbf)
{
    int o = blockIdx.x;        // 128 blocks
    int k = threadIdx.x;       // 256 threads
    float v = (k < 128) ? Wself[o * 128 + k] : Wnode[o * 128 + (k - 128)];
    Wbf[o * 256 + k] = f2bf(v);
}

// ---------------------------------------------------------------------------
// 6) gather-reduce: Abf[b,d,:] = bf16( sum_{e:dst=d} X[b,src,:] ); S = sum ea
//    one wave per (b,d); cooperative index load + shfl broadcast
// ---------------------------------------------------------------------------
__global__ __launch_bounds__(256) void gather_kernel(
    const float* __restrict__ X, const float* __restrict__ EA,
    const int* __restrict__ row_ptr, const int* __restrict__ ssrc,
    const int* __restrict__ seid, unsigned short* __restrict__ Abf,
    float* __restrict__ S)
{
    int wid = (blockIdx.x * 256 + threadIdx.x) >> 6;   // 0 .. M_-1
    int lane = threadIdx.x & 63;
    int b = wid / V_;
    int d = wid - b * V_;
    int k0 = row_ptr[d];
    int k1 = row_ptr[d + 1];
    const float* Xb = X + (size_t)b * V_ * DIN + lane * 2;
    float ax = 0.0f, ay = 0.0f;
    float ea = 0.0f;
    for (int kb = k0; kb < k1; kb += 64) {
        int cnt = min(64, k1 - kb);
        int msrc = 0;
        if (lane < cnt) {
            msrc = ssrc[kb + lane];
            ea += EA[(size_t)b * E_ + seid[kb + lane]];
        }
        int j = 0;
        for (; j + 4 <= cnt; j += 4) {
            int s0 = __shfl(msrc, j);
            int s1 = __shfl(msrc, j + 1);
            int s2 = __shfl(msrc, j + 2);
            int s3 = __shfl(msrc, j + 3);
            float2 v0 = *(const float2*)(Xb + (size_t)s0 * DIN);
            float2 v1 = *(const float2*)(Xb + (size_t)s1 * DIN);
            float2 v2 = *(const float2*)(Xb + (size_t)s2 * DIN);
            float2 v3 = *(const float2*)(Xb + (size_t)s3 * DIN);
            ax += v0.x + v1.x + v2.x + v3.x;
            ay += v0.y + v1.y + v2.y + v3.y;
        }
        for (; j < cnt; ++j) {
            int s = __shfl(msrc, j);
            float2 v = *(const float2*)(Xb + (size_t)s * DIN);
            ax += v.x; ay += v.y;
        }
    }
    // edge_attr wave reduction
    for (int off = 32; off; off >>= 1) ea += __shfl_down(ea, off);
    if (lane == 0) S[wid] = ea;
    ushort2 o;
    o.x = f2bf(ax); o.y = f2bf(ay);
    *(ushort2*)(Abf + (size_t)wid * DIN + lane * 2) = o;
}

// ---------------------------------------------------------------------------
// 7) MFMA GEMM: H = [Xbf|Abf] @ Wbf^T + b_self + S*w_edge
//    block = 64 rows x 128 cols, 4 waves, no LDS.
// ---------------------------------------------------------------------------
__global__ __launch_bounds__(256) void mfma_gemm_kernel(
    const unsigned short* __restrict__ Xbf, const unsigned short* __restrict__ Abf,
    const unsigned short* __restrict__ Wbf, const float* __restrict__ S,
    const float* __restrict__ bself, const float* __restrict__ wedge,
    float* __restrict__ H)
{
    const int t = threadIdx.x;
    const int wave = t >> 6;
    const int lane = t & 63;
    const int quad = lane >> 4;
    const int ln = lane & 15;
    const int m = blockIdx.x * 64 + wave * 16 + ln;     // A-frag row

    f32x4 acc[8];
#pragma unroll
    for (int nt = 0; nt < 8; ++nt) acc[nt] = (f32x4){0.f, 0.f, 0.f, 0.f};

    const short* Xp = (const short*)Xbf + (size_t)m * DIN + quad * 8;
    const short* Ap = (const short*)Abf + (size_t)m * DIN + quad * 8;
    const short* Wp = (const short*)Wbf + (size_t)ln * 256 + quad * 8;

#pragma unroll
    for (int ks = 0; ks < 4; ++ks) {
        short8 af = *(const short8*)(Xp + ks * 32);
#pragma unroll
        for (int nt = 0; nt < 8; ++nt) {
            short8 bf = *(const short8*)(Wp + (size_t)nt * 16 * 256 + ks * 32);
            acc[nt] = __builtin_amdgcn_mfma_f32_16x16x32_bf16(af, bf, acc[nt], 0, 0, 0);
        }
    }
#pragma unroll
    for (int ks = 0; ks < 4; ++ks) {
        short8 af = *(const short8*)(Ap + ks * 32);
#pragma unroll
        for (int nt = 0; nt < 8; ++nt) {
            short8 bf = *(const short8*)(Wp + (size_t)nt * 16 * 256 + 128 + ks * 32);
            acc[nt] = __builtin_amdgcn_mfma_f32_16x16x32_bf16(af, bf, acc[nt], 0, 0, 0);
        }
    }

    // epilogue: C/D layout col = ln, row = quad*4 + r
    const int rbase = blockIdx.x * 64 + wave * 16 + quad * 4;
    float sv[4];
#pragma unroll
    for (int r = 0; r < 4; ++r) sv[r] = S[rbase + r];
    float bs[8], we[8];
#pragma unroll
    for (int nt = 0; nt < 8; ++nt) {
        int c = nt * 16 + ln;
        bs[nt] = bself[c];
        we[nt] = wedge[c];
    }
#pragma unroll
    for (int r = 0; r < 4; ++r) {
        float* Hr = H + (size_t)(rbase + r) * DOUT + ln;
#pragma unroll
        for (int nt = 0; nt < 8; ++nt) {
            Hr[nt * 16] = acc[nt][r] + bs[nt] + sv[r] * we[nt];
        }
    }
}

// ---------------------------------------------------------------------------
// 8) per-channel stats reduction over H
// ---------------------------------------------------------------------------
__global__ __launch_bounds__(256) void stats_kernel(
    const float* __restrict__ H, float* __restrict__ gsum,
    float* __restrict__ gsumsq)
{
    __shared__ float cs[128];
    __shared__ float css[128];
    const int t = threadIdx.x;
    if (t < 128) { cs[t] = 0.0f; css[t] = 0.0f; }
    __syncthreads();
    const int total4 = M_ * DOUT / 4;
    const int stride = gridDim.x * 256;
    int idx = blockIdx.x * 256 + t;
    const int c4 = (idx & 31) * 4;         // invariant: stride % 32 == 0
    float s0 = 0, s1 = 0, s2 = 0, s3 = 0;
    float q0 = 0, q1 = 0, q2 = 0, q3 = 0;
    for (; idx < total4; idx += stride) {
        float4 h = ((const float4*)H)[idx];
        s0 += h.x; s1 += h.y; s2 += h.z; s3 += h.w;
        q0 += h.x * h.x; q1 += h.y * h.y; q2 += h.z * h.z; q3 += h.w * h.w;
    }
    atomicAdd(&cs[c4 + 0], s0); atomicAdd(&cs[c4 + 1], s1);
    atomicAdd(&cs[c4 + 2], s2); atomicAdd(&cs[c4 + 3], s3);
    atomicAdd(&css[c4 + 0], q0); atomicAdd(&css[c4 + 1], q1);
    atomicAdd(&css[c4 + 2], q2); atomicAdd(&css[c4 + 3], q3);
    __syncthreads();
    if (t < 128) {
        atomicAdd(&gsum[t], cs[t]);
        atomicAdd(&gsumsq[t], css[t]);
    }
}

// ---------------------------------------------------------------------------
// 9) finalize stats -> scale/shift
// ---------------------------------------------------------------------------
__global__ void finalize_kernel(
    const float* __restrict__ gsum, const float* __restrict__ gsumsq,
    const float* __restrict__ gamma, const float* __restrict__ beta,
    float* __restrict__ scale, float* __restrict__ shift)
{
    int o = threadIdx.x;  // 128 threads
    float mean = gsum[o] * NINV;
    float var = gsumsq[o] * NINV - mean * mean;
    float rstd = rsqrtf(var + BN_EPS);
    float sc = gamma[o] * rstd;
    scale[o] = sc;
    shift[o] = beta[o] - mean * sc;
}

// ---------------------------------------------------------------------------
// 10) normalize + ReLU in place on d_out
// ---------------------------------------------------------------------------
__global__ __launch_bounds__(256) void norm_relu_kernel(
    float* __restrict__ H, const float* __restrict__ scale,
    const float* __restrict__ shift)
{
    int idx = blockIdx.x * 256 + threadIdx.x;   // over M_*128/4 float4s
    int o4 = (idx & 31) * 4;
    float4 h = ((const float4*)H)[idx];
    float4 sc = *(const float4*)(scale + o4);
    float4 sh = *(const float4*)(shift + o4);
    h.x = fmaxf(h.x * sc.x + sh.x, 0.0f);
    h.y = fmaxf(h.y * sc.y + sh.y, 0.0f);
    h.z = fmaxf(h.z * sc.z + sh.z, 0.0f);
    h.w = fmaxf(h.w * sc.w + sh.w, 0.0f);
    ((float4*)H)[idx] = h;
}

// ---------------------------------------------------------------------------
extern "C" void kernel_launch(void* const* d_in, const int* in_sizes, int n_in,
                              void* d_out, int out_size, void* d_ws, size_t ws_size,
                              hipStream_t stream)
{
    const float* X      = (const float*)d_in[0];
    const float* EA     = (const float*)d_in[1];
    const float* Wnode  = (const float*)d_in[2];
    const float* Wedge  = (const float*)d_in[3];
    const float* Wself  = (const float*)d_in[4];
    const float* bself  = (const float*)d_in[5];
    const float* gamma  = (const float*)d_in[6];
    const float* beta   = (const float*)d_in[7];
    const int*   EI     = (const int*)d_in[8];

    int*   wsI    = (int*)d_ws;
    float* wsF    = (float*)d_ws;
    int*   counts = wsI + WS_COUNTS;
    float* gsum   = wsF + WS_SUM;
    float* gsumsq = wsF + WS_SUMSQ;
    float* scale  = wsF + WS_SCALE;
    float* shift  = wsF + WS_SHIFT;
    int*   rowptr = wsI + WS_ROWPTR;
    int*   cursor = wsI + WS_CURSOR;
    int*   ssrc   = wsI + WS_SSRC;
    int*   seid   = wsI + WS_SEID;
    float* S      = wsF + WS_S;
    unsigned short* Wbf = (unsigned short*)(wsI + WS_WBF);
    unsigned short* Xbf = (unsigned short*)(wsI + WS_XBF);
    unsigned short* Abf = (unsigned short*)(wsI + WS_ABF);
    float* H      = (float*)d_out;

    hipMemsetAsync(d_ws, 0, (size_t)WS_ZERO_UNITS * 4, stream);

    // CSR build
    hist_kernel<<<(E_ + 255) / 256, 256, 0, stream>>>(EI, counts);
    scan_kernel<<<1, 256, 0, stream>>>(counts, rowptr, cursor);
    bucket_kernel<<<(E_ + 255) / 256, 256, 0, stream>>>(EI, cursor, ssrc, seid);

    // bf16 prepasses
    xcvt_kernel<<<(M_ * DIN / 4) / 256, 256, 0, stream>>>(X, Xbf);
    wcvt_kernel<<<128, 256, 0, stream>>>(Wself, Wnode, Wbf);

    // gather-reduce -> Abf, S
    gather_kernel<<<M_ / 4, 256, 0, stream>>>(X, EA, rowptr, ssrc, seid, Abf, S);

    // MFMA GEMM -> H
    mfma_gemm_kernel<<<M_ / 64, 256, 0, stream>>>(Xbf, Abf, Wbf, S, bself, Wedge, H);

    // batchnorm stats + finalize + norm/relu
    stats_kernel<<<1024, 256, 0, stream>>>(H, gsum, gsumsq);
    finalize_kernel<<<1, 128, 0, stream>>>(gsum, gsumsq, gamma, beta, scale, shift);
    norm_relu_kernel<<<(M_ * DOUT / 4) / 256, 256, 0, stream>>>(H, scale, shift);
}

// Round 4
// 253.812 us; speedup vs baseline: 9.8930x; 1.2096x over previous
//
#include <hip/hip_runtime.h>

// Problem constants
#define B_ 8
#define V_ 10000
#define E_ 160000
#define DIN 128
#define DOUT 128
#define M_ (B_*V_)          // 80000 rows
#define NINV (1.0f/80000.0f)
#define BN_EPS 1e-5f

// Workspace layout (4-byte units):
#define WS_COUNTS  0            // V_            (zeroed)
#define WS_SUM     10000        // 128           (zeroed)
#define WS_SUMSQ   10128        // 128           (zeroed)
#define WS_ROWPTR  10512        // V_+1
#define WS_CURSOR  20513        // V_
#define WS_SSRC    30513        // E_
#define WS_SEID    190513       // E_
#define WS_S       350513       // M_
#define WS_WBF     430516       // 16384 units = 32768 bf16 (16B aligned)
#define WS_XBF     446900       // 5,120,000 units = 10.24M bf16
#define WS_ABF     5566900      // 5,120,000 units
#define WS_ZERO_UNITS 10256     // counts + gsum + gsumsq

typedef __attribute__((ext_vector_type(8))) short short8;
typedef __attribute__((ext_vector_type(4))) float f32x4;

__device__ inline unsigned short f2bf(float x) {
    union { float f; unsigned u; } v; v.f = x;
    unsigned r = v.u + 0x7FFFu + ((v.u >> 16) & 1u);   // RNE
    return (unsigned short)(r >> 16);
}
__device__ inline float bf2f(unsigned short u) {
    union { unsigned u; float f; } v; v.u = ((unsigned)u) << 16;
    return v.f;
}

// ---------------------------------------------------------------------------
// 1) histogram of dst
// ---------------------------------------------------------------------------
__global__ __launch_bounds__(256) void hist_kernel(
    const int* __restrict__ EI, int* __restrict__ counts)
{
    int e = blockIdx.x * 256 + threadIdx.x;
    if (e < E_) atomicAdd(&counts[EI[2 * e + 1]], 1);
}

// ---------------------------------------------------------------------------
// 2) exclusive prefix sum over counts -> row_ptr, cursor (single block)
// ---------------------------------------------------------------------------
__global__ __launch_bounds__(256) void scan_kernel(
    const int* __restrict__ counts, int* __restrict__ row_ptr,
    int* __restrict__ cursor)
{
    __shared__ int psum[256];
    const int t = threadIdx.x;
    const int base = t * 40;              // 256*40 = 10240 >= V_
    int local[40];
    int s = 0;
#pragma unroll
    for (int i = 0; i < 40; ++i) {
        int idx = base + i;
        int c = (idx < V_) ? counts[idx] : 0;
        local[i] = s;
        s += c;
    }
    psum[t] = s;
    __syncthreads();
    for (int off = 1; off < 256; off <<= 1) {
        int v = (t >= off) ? psum[t - off] : 0;
        __syncthreads();
        psum[t] += v;
        __syncthreads();
    }
    int excl = (t == 0) ? 0 : psum[t - 1];
#pragma unroll
    for (int i = 0; i < 40; ++i) {
        int idx = base + i;
        if (idx < V_) {
            int rp = excl + local[i];
            row_ptr[idx] = rp;
            cursor[idx] = rp;
        }
    }
    if (t == 255) row_ptr[V_] = psum[255];
}

// ---------------------------------------------------------------------------
// 3) scatter edges into dst-sorted buckets
// ---------------------------------------------------------------------------
__global__ __launch_bounds__(256) void bucket_kernel(
    const int* __restrict__ EI, int* __restrict__ cursor,
    int* __restrict__ ssrc, int* __restrict__ seid)
{
    int e = blockIdx.x * 256 + threadIdx.x;
    if (e < E_) {
        int src = EI[2 * e];
        int dst = EI[2 * e + 1];
        int p = atomicAdd(&cursor[dst], 1);
        ssrc[p] = src;
        seid[p] = e;
    }
}

// ---------------------------------------------------------------------------
// 4) X -> bf16 prepass
// ---------------------------------------------------------------------------
__global__ __launch_bounds__(256) void xcvt_kernel(
    const float* __restrict__ X, unsigned short* __restrict__ Xbf)
{
    int idx = blockIdx.x * 256 + threadIdx.x;      // over M_*DIN/4
    float4 v = ((const float4*)X)[idx];
    ushort4 o;
    o.x = f2bf(v.x); o.y = f2bf(v.y); o.z = f2bf(v.z); o.w = f2bf(v.w);
    ((ushort4*)Xbf)[idx] = o;
}

// ---------------------------------------------------------------------------
// 5) pack [W_self | W_node] -> Wbf[o][256] bf16
// ---------------------------------------------------------------------------
__global__ __launch_bounds__(256) void wcvt_kernel(
    const float* __restrict__ Wself, const float* __restrict__ Wnode,
    unsigned short* __restrict__ Wbf)
{
    int o = blockIdx.x;        // 128 blocks
    int k = threadIdx.x;       // 256 threads
    float v = (k < 128) ? Wself[o * 128 + k] : Wnode[o * 128 + (k - 128)];
    Wbf[o * 256 + k] = f2bf(v);
}

// ---------------------------------------------------------------------------
// 6) gather-reduce from bf16 X, batch-per-XCD swizzled:
//    Abf[b,d,:] = bf16( sum_{e:dst=d} Xbf[b,src,:] ); S[b,d] = sum ea
//    one wave per (b,d); b = blockIdx & 7 so each XCD stays on one batch
//    (per-batch Xbf 2.56MB + EA 0.64MB fit in a 4MB XCD L2)
// ---------------------------------------------------------------------------
__global__ __launch_bounds__(256) void gather_kernel(
    const unsigned short* __restrict__ Xbf, const float* __restrict__ EA,
    const int* __restrict__ row_ptr, const int* __restrict__ ssrc,
    const int* __restrict__ seid, unsigned short* __restrict__ Abf,
    float* __restrict__ S)
{
    const int b = blockIdx.x & 7;             // batch -> XCD
    const int dblk = blockIdx.x >> 3;         // 0..2499
    const int w = threadIdx.x >> 6;           // 4 waves/block
    const int lane = threadIdx.x & 63;
    const int d = dblk * 4 + w;
    const int wid = b * V_ + d;
    const int k0 = row_ptr[d];
    const int k1 = row_ptr[d + 1];
    const unsigned short* Xb = Xbf + (size_t)b * V_ * DIN + lane * 2;
    const float* EAb = EA + (size_t)b * E_;
    float ax = 0.0f, ay = 0.0f;
    float ea = 0.0f;
    for (int kb = k0; kb < k1; kb += 64) {
        int cnt = min(64, k1 - kb);
        int msrc = 0;
        if (lane < cnt) {
            msrc = ssrc[kb + lane];
            ea += EAb[seid[kb + lane]];
        }
        int j = 0;
        for (; j + 4 <= cnt; j += 4) {
            int s0 = __shfl(msrc, j);
            int s1 = __shfl(msrc, j + 1);
            int s2 = __shfl(msrc, j + 2);
            int s3 = __shfl(msrc, j + 3);
            ushort2 v0 = *(const ushort2*)(Xb + (size_t)s0 * DIN);
            ushort2 v1 = *(const ushort2*)(Xb + (size_t)s1 * DIN);
            ushort2 v2 = *(const ushort2*)(Xb + (size_t)s2 * DIN);
            ushort2 v3 = *(const ushort2*)(Xb + (size_t)s3 * DIN);
            ax += bf2f(v0.x) + bf2f(v1.x) + bf2f(v2.x) + bf2f(v3.x);
            ay += bf2f(v0.y) + bf2f(v1.y) + bf2f(v2.y) + bf2f(v3.y);
        }
        for (; j < cnt; ++j) {
            int s = __shfl(msrc, j);
            ushort2 v = *(const ushort2*)(Xb + (size_t)s * DIN);
            ax += bf2f(v.x); ay += bf2f(v.y);
        }
    }
    for (int off = 32; off; off >>= 1) ea += __shfl_down(ea, off);
    if (lane == 0) S[wid] = ea;
    ushort2 o;
    o.x = f2bf(ax); o.y = f2bf(ay);
    *(ushort2*)(Abf + (size_t)wid * DIN + lane * 2) = o;
}

// ---------------------------------------------------------------------------
// 7) MFMA GEMM + fused BN stats:
//    H = [Xbf|Abf] @ Wbf^T + b_self + S*w_edge; gsum/gsumsq += per-channel
// ---------------------------------------------------------------------------
__global__ __launch_bounds__(256) void mfma_gemm_kernel(
    const unsigned short* __restrict__ Xbf, const unsigned short* __restrict__ Abf,
    const unsigned short* __restrict__ Wbf, const float* __restrict__ S,
    const float* __restrict__ bself, const float* __restrict__ wedge,
    float* __restrict__ H, float* __restrict__ gsum, float* __restrict__ gsumsq)
{
    __shared__ float cs[128];
    __shared__ float css[128];
    const int t = threadIdx.x;
    const int wave = t >> 6;
    const int lane = t & 63;
    const int quad = lane >> 4;
    const int ln = lane & 15;
    const int m = blockIdx.x * 64 + wave * 16 + ln;     // A-frag row

    if (t < 128) { cs[t] = 0.0f; css[t] = 0.0f; }

    f32x4 acc[8];
#pragma unroll
    for (int nt = 0; nt < 8; ++nt) acc[nt] = (f32x4){0.f, 0.f, 0.f, 0.f};

    const short* Xp = (const short*)Xbf + (size_t)m * DIN + quad * 8;
    const short* Ap = (const short*)Abf + (size_t)m * DIN + quad * 8;
    const short* Wp = (const short*)Wbf + (size_t)ln * 256 + quad * 8;

#pragma unroll
    for (int ks = 0; ks < 4; ++ks) {
        short8 af = *(const short8*)(Xp + ks * 32);
#pragma unroll
        for (int nt = 0; nt < 8; ++nt) {
            short8 bf = *(const short8*)(Wp + (size_t)nt * 16 * 256 + ks * 32);
            acc[nt] = __builtin_amdgcn_mfma_f32_16x16x32_bf16(af, bf, acc[nt], 0, 0, 0);
        }
    }
#pragma unroll
    for (int ks = 0; ks < 4; ++ks) {
        short8 af = *(const short8*)(Ap + ks * 32);
#pragma unroll
        for (int nt = 0; nt < 8; ++nt) {
            short8 bf = *(const short8*)(Wp + (size_t)nt * 16 * 256 + 128 + ks * 32);
            acc[nt] = __builtin_amdgcn_mfma_f32_16x16x32_bf16(af, bf, acc[nt], 0, 0, 0);
        }
    }

    // epilogue: C/D layout col = ln, row = quad*4 + r
    const int rbase = blockIdx.x * 64 + wave * 16 + quad * 4;
    float sv[4];
#pragma unroll
    for (int r = 0; r < 4; ++r) sv[r] = S[rbase + r];
    float bs[8], we[8];
#pragma unroll
    for (int nt = 0; nt < 8; ++nt) {
        int c = nt * 16 + ln;
        bs[nt] = bself[c];
        we[nt] = wedge[c];
    }
    float psum[8], psq[8];
#pragma unroll
    for (int nt = 0; nt < 8; ++nt) { psum[nt] = 0.0f; psq[nt] = 0.0f; }
#pragma unroll
    for (int r = 0; r < 4; ++r) {
        float* Hr = H + (size_t)(rbase + r) * DOUT + ln;
#pragma unroll
        for (int nt = 0; nt < 8; ++nt) {
            float h = acc[nt][r] + bs[nt] + sv[r] * we[nt];
            Hr[nt * 16] = h;
            psum[nt] += h;
            psq[nt] += h * h;
        }
    }
    // reduce across quads (lanes ln, ln+16, ln+32, ln+48)
#pragma unroll
    for (int nt = 0; nt < 8; ++nt) {
        psum[nt] += __shfl_down(psum[nt], 32);
        psum[nt] += __shfl_down(psum[nt], 16);
        psq[nt] += __shfl_down(psq[nt], 32);
        psq[nt] += __shfl_down(psq[nt], 16);
    }
    __syncthreads();   // cs/css zeros visible
    if (lane < 16) {
#pragma unroll
        for (int nt = 0; nt < 8; ++nt) {
            atomicAdd(&cs[nt * 16 + ln], psum[nt]);
            atomicAdd(&css[nt * 16 + ln], psq[nt]);
        }
    }
    __syncthreads();
    if (t < 128) {
        atomicAdd(&gsum[t], cs[t]);
        atomicAdd(&gsumsq[t], css[t]);
    }
}

// ---------------------------------------------------------------------------
// 8) normalize + ReLU in place (finalize fused: scale/shift recomputed per
//    thread from gsum/gsumsq — L1-hot 1KB tables)
// ---------------------------------------------------------------------------
__global__ __launch_bounds__(256) void norm_relu_kernel(
    float* __restrict__ H, const float* __restrict__ gsum,
    const float* __restrict__ gsumsq, const float* __restrict__ gamma,
    const float* __restrict__ beta)
{
    int idx = blockIdx.x * 256 + threadIdx.x;   // over M_*128/4 float4s
    int o4 = (idx & 31) * 4;
    float4 s = *(const float4*)(gsum + o4);
    float4 q = *(const float4*)(gsumsq + o4);
    float4 g = *(const float4*)(gamma + o4);
    float4 bt = *(const float4*)(beta + o4);
    float4 sc, sh;
    {
        float m0 = s.x * NINV, m1 = s.y * NINV, m2 = s.z * NINV, m3 = s.w * NINV;
        float r0 = rsqrtf(q.x * NINV - m0 * m0 + BN_EPS);
        float r1 = rsqrtf(q.y * NINV - m1 * m1 + BN_EPS);
        float r2 = rsqrtf(q.z * NINV - m2 * m2 + BN_EPS);
        float r3 = rsqrtf(q.w * NINV - m3 * m3 + BN_EPS);
        sc.x = g.x * r0; sc.y = g.y * r1; sc.z = g.z * r2; sc.w = g.w * r3;
        sh.x = bt.x - m0 * sc.x; sh.y = bt.y - m1 * sc.y;
        sh.z = bt.z - m2 * sc.z; sh.w = bt.w - m3 * sc.w;
    }
    float4 h = ((const float4*)H)[idx];
    h.x = fmaxf(h.x * sc.x + sh.x, 0.0f);
    h.y = fmaxf(h.y * sc.y + sh.y, 0.0f);
    h.z = fmaxf(h.z * sc.z + sh.z, 0.0f);
    h.w = fmaxf(h.w * sc.w + sh.w, 0.0f);
    ((float4*)H)[idx] = h;
}

// ---------------------------------------------------------------------------
extern "C" void kernel_launch(void* const* d_in, const int* in_sizes, int n_in,
                              void* d_out, int out_size, void* d_ws, size_t ws_size,
                              hipStream_t stream)
{
    const float* X      = (const float*)d_in[0];
    const float* EA     = (const float*)d_in[1];
    const float* Wnode  = (const float*)d_in[2];
    const float* Wedge  = (const float*)d_in[3];
    const float* Wself  = (const float*)d_in[4];
    const float* bself  = (const float*)d_in[5];
    const float* gamma  = (const float*)d_in[6];
    const float* beta   = (const float*)d_in[7];
    const int*   EI     = (const int*)d_in[8];

    int*   wsI    = (int*)d_ws;
    float* wsF    = (float*)d_ws;
    int*   counts = wsI + WS_COUNTS;
    float* gsum   = wsF + WS_SUM;
    float* gsumsq = wsF + WS_SUMSQ;
    int*   rowptr = wsI + WS_ROWPTR;
    int*   cursor = wsI + WS_CURSOR;
    int*   ssrc   = wsI + WS_SSRC;
    int*   seid   = wsI + WS_SEID;
    float* S      = wsF + WS_S;
    unsigned short* Wbf = (unsigned short*)(wsI + WS_WBF);
    unsigned short* Xbf = (unsigned short*)(wsI + WS_XBF);
    unsigned short* Abf = (unsigned short*)(wsI + WS_ABF);
    float* H      = (float*)d_out;

    hipMemsetAsync(d_ws, 0, (size_t)WS_ZERO_UNITS * 4, stream);

    // CSR build
    hist_kernel<<<(E_ + 255) / 256, 256, 0, stream>>>(EI, counts);
    scan_kernel<<<1, 256, 0, stream>>>(counts, rowptr, cursor);
    bucket_kernel<<<(E_ + 255) / 256, 256, 0, stream>>>(EI, cursor, ssrc, seid);

    // bf16 prepasses
    xcvt_kernel<<<(M_ * DIN / 4) / 256, 256, 0, stream>>>(X, Xbf);
    wcvt_kernel<<<128, 256, 0, stream>>>(Wself, Wnode, Wbf);

    // gather-reduce -> Abf, S  (batch-per-XCD swizzle)
    gather_kernel<<<M_ / 4, 256, 0, stream>>>(Xbf, EA, rowptr, ssrc, seid, Abf, S);

    // MFMA GEMM + stats -> H, gsum, gsumsq
    mfma_gemm_kernel<<<M_ / 64, 256, 0, stream>>>(Xbf, Abf, Wbf, S, bself, Wedge,
                                                  H, gsum, gsumsq);

    // normalize + relu (finalize fused)
    norm_relu_kernel<<<(M_ * DOUT / 4) / 256, 256, 0, stream>>>(H, gsum, gsumsq,
                                                                gamma, beta);
}

// Round 5
// 235.695 us; speedup vs baseline: 10.6534x; 1.0769x over previous
//
#include <hip/hip_runtime.h>

// Problem constants
#define B_ 8
#define V_ 10000
#define E_ 160000
#define DIN 128
#define DOUT 128
#define M_ (B_*V_)          // 80000 rows
#define NINV (1.0f/80000.0f)
#define BN_EPS 1e-5f

// Workspace layout (4-byte units):
#define WS_COUNTS  0            // V_            (zeroed)
#define WS_SUM     10000        // 128           (zeroed)
#define WS_SUMSQ   10128        // 128           (zeroed)
#define WS_ROWPTR  10512        // V_+1
#define WS_CURSOR  20513        // V_
#define WS_SSRC    30513        // E_
#define WS_SEID    190513       // E_
#define WS_S       350513       // M_
#define WS_WPK     430516       // 16384 units = 32768 bf16 = 64KB (16B aligned)
#define WS_XBF     446900       // 5,120,000 units = 10.24M bf16
#define WS_ABF     5566900      // 5,120,000 units
#define WS_ZERO_UNITS 10256     // counts + gsum + gsumsq

typedef __attribute__((ext_vector_type(8))) short short8;
typedef __attribute__((ext_vector_type(4))) float f32x4;

__device__ inline unsigned short f2bf(float x) {
    union { float f; unsigned u; } v; v.f = x;
    unsigned r = v.u + 0x7FFFu + ((v.u >> 16) & 1u);   // RNE
    return (unsigned short)(r >> 16);
}
__device__ inline float bf2f(unsigned short u) {
    union { unsigned u; float f; } v; v.u = ((unsigned)u) << 16;
    return v.f;
}

// ---------------------------------------------------------------------------
// 1) fused prep: X->bf16 row-major (blocks 0..9999)
//              + W fragment-major pack (blocks 10000..10015)
//              + dst histogram (blocks 10016..10640)
// Wpk layout: for ks in [0,8), nt in [0,8), lane in [0,64):
//   Wpk[((ks*8+nt)*64 + lane)*8 + j] = Wcomb[nt*16 + (lane&15)][ks*32 + (lane>>4)*8 + j]
//   where Wcomb[o][k] = k<128 ? Wself[o][k] : Wnode[o][k-128]
// ---------------------------------------------------------------------------
__global__ __launch_bounds__(256) void prep_kernel(
    const float* __restrict__ X, unsigned short* __restrict__ Xbf,
    const float* __restrict__ Wself, const float* __restrict__ Wnode,
    unsigned short* __restrict__ Wpk,
    const int* __restrict__ EI, int* __restrict__ counts)
{
    const int blk = blockIdx.x;
    const int t = threadIdx.x;
    if (blk < 10000) {
        int idx = blk * 256 + t;                 // over M_*DIN/4
        float4 v = ((const float4*)X)[idx];
        ushort4 o;
        o.x = f2bf(v.x); o.y = f2bf(v.y); o.z = f2bf(v.z); o.w = f2bf(v.w);
        ((ushort4*)Xbf)[idx] = o;
    } else if (blk < 10016) {
        int g = (blk - 10000) * 256 + t;         // 0..4095
        int pair = g >> 6;                       // (ks,nt)
        int lane = g & 63;
        int ks = pair >> 3;
        int nt = pair & 7;
        int o = nt * 16 + (lane & 15);
        int k = ks * 32 + (lane >> 4) * 8;
        const float* wsrc = (k < 128) ? (Wself + o * 128 + k)
                                      : (Wnode + o * 128 + (k - 128));
        unsigned short* dst = Wpk + ((size_t)pair * 64 + lane) * 8;
#pragma unroll
        for (int j = 0; j < 8; ++j) dst[j] = f2bf(wsrc[j]);
    } else {
        int e = (blk - 10016) * 256 + t;
        if (e < E_) atomicAdd(&counts[EI[2 * e + 1]], 1);
    }
}

// ---------------------------------------------------------------------------
// 2) exclusive prefix sum over counts -> row_ptr, cursor (single block)
// ---------------------------------------------------------------------------
__global__ __launch_bounds__(256) void scan_kernel(
    const int* __restrict__ counts, int* __restrict__ row_ptr,
    int* __restrict__ cursor)
{
    __shared__ int psum[256];
    const int t = threadIdx.x;
    const int base = t * 40;              // 256*40 = 10240 >= V_
    int local[40];
    int s = 0;
#pragma unroll
    for (int i = 0; i < 40; ++i) {
        int idx = base + i;
        int c = (idx < V_) ? counts[idx] : 0;
        local[i] = s;
        s += c;
    }
    psum[t] = s;
    __syncthreads();
    for (int off = 1; off < 256; off <<= 1) {
        int v = (t >= off) ? psum[t - off] : 0;
        __syncthreads();
        psum[t] += v;
        __syncthreads();
    }
    int excl = (t == 0) ? 0 : psum[t - 1];
#pragma unroll
    for (int i = 0; i < 40; ++i) {
        int idx = base + i;
        if (idx < V_) {
            int rp = excl + local[i];
            row_ptr[idx] = rp;
            cursor[idx] = rp;
        }
    }
    if (t == 255) row_ptr[V_] = psum[255];
}

// ---------------------------------------------------------------------------
// 3) scatter edges into dst-sorted buckets
// ---------------------------------------------------------------------------
__global__ __launch_bounds__(256) void bucket_kernel(
    const int* __restrict__ EI, int* __restrict__ cursor,
    int* __restrict__ ssrc, int* __restrict__ seid)
{
    int e = blockIdx.x * 256 + threadIdx.x;
    if (e < E_) {
        int src = EI[2 * e];
        int dst = EI[2 * e + 1];
        int p = atomicAdd(&cursor[dst], 1);
        ssrc[p] = src;
        seid[p] = e;
    }
}

// ---------------------------------------------------------------------------
// 4) gather-reduce from bf16 X, batch-per-XCD swizzled:
//    Abf[b,d,:] = bf16( sum_{e:dst=d} Xbf[b,src,:] ); S[b,d] = sum ea
// ---------------------------------------------------------------------------
__global__ __launch_bounds__(256) void gather_kernel(
    const unsigned short* __restrict__ Xbf, const float* __restrict__ EA,
    const int* __restrict__ row_ptr, const int* __restrict__ ssrc,
    const int* __restrict__ seid, unsigned short* __restrict__ Abf,
    float* __restrict__ S)
{
    const int b = blockIdx.x & 7;             // batch -> XCD
    const int dblk = blockIdx.x >> 3;         // 0..2499
    const int w = threadIdx.x >> 6;           // 4 waves/block
    const int lane = threadIdx.x & 63;
    const int d = dblk * 4 + w;
    const int wid = b * V_ + d;
    const int k0 = row_ptr[d];
    const int k1 = row_ptr[d + 1];
    const unsigned short* Xb = Xbf + (size_t)b * V_ * DIN + lane * 2;
    const float* EAb = EA + (size_t)b * E_;
    float ax = 0.0f, ay = 0.0f;
    float ea = 0.0f;
    for (int kb = k0; kb < k1; kb += 64) {
        int cnt = min(64, k1 - kb);
        int msrc = 0;
        if (lane < cnt) {
            msrc = ssrc[kb + lane];
            ea += EAb[seid[kb + lane]];
        }
        int j = 0;
        for (; j + 4 <= cnt; j += 4) {
            int s0 = __shfl(msrc, j);
            int s1 = __shfl(msrc, j + 1);
            int s2 = __shfl(msrc, j + 2);
            int s3 = __shfl(msrc, j + 3);
            ushort2 v0 = *(const ushort2*)(Xb + (size_t)s0 * DIN);
            ushort2 v1 = *(const ushort2*)(Xb + (size_t)s1 * DIN);
            ushort2 v2 = *(const ushort2*)(Xb + (size_t)s2 * DIN);
            ushort2 v3 = *(const ushort2*)(Xb + (size_t)s3 * DIN);
            ax += bf2f(v0.x) + bf2f(v1.x) + bf2f(v2.x) + bf2f(v3.x);
            ay += bf2f(v0.y) + bf2f(v1.y) + bf2f(v2.y) + bf2f(v3.y);
        }
        for (; j < cnt; ++j) {
            int s = __shfl(msrc, j);
            ushort2 v = *(const ushort2*)(Xb + (size_t)s * DIN);
            ax += bf2f(v.x); ay += bf2f(v.y);
        }
    }
    for (int off = 32; off; off >>= 1) ea += __shfl_down(ea, off);
    if (lane == 0) S[wid] = ea;
    ushort2 o;
    o.x = f2bf(ax); o.y = f2bf(ay);
    *(ushort2*)(Abf + (size_t)wid * DIN + lane * 2) = o;
}

// ---------------------------------------------------------------------------
// 5) MFMA GEMM + fused BN stats.
//    Block = 128 rows x 128 cols, 4 waves; wave = 32 rows (2 m-tiles).
//    B-frags from fragment-packed Wpk: base + lane*16 (fully coalesced).
// ---------------------------------------------------------------------------
__global__ __launch_bounds__(256) void mfma_gemm_kernel(
    const unsigned short* __restrict__ Xbf, const unsigned short* __restrict__ Abf,
    const unsigned short* __restrict__ Wpk, const float* __restrict__ S,
    const float* __restrict__ bself, const float* __restrict__ wedge,
    float* __restrict__ H, float* __restrict__ gsum, float* __restrict__ gsumsq)
{
    __shared__ float cs[128];
    __shared__ float css[128];
    const int t = threadIdx.x;
    const int wave = t >> 6;
    const int lane = t & 63;
    const int quad = lane >> 4;
    const int ln = lane & 15;
    const int rowbase = blockIdx.x * 128 + wave * 32;
    const int m0 = rowbase + ln;          // m-tile 0 A-frag row
    const int m1 = rowbase + 16 + ln;     // m-tile 1 A-frag row

    if (t < 128) { cs[t] = 0.0f; css[t] = 0.0f; }

    f32x4 acc[2][8];
#pragma unroll
    for (int mt = 0; mt < 2; ++mt)
#pragma unroll
        for (int nt = 0; nt < 8; ++nt) acc[mt][nt] = (f32x4){0.f, 0.f, 0.f, 0.f};

    const short* X0 = (const short*)Xbf + (size_t)m0 * DIN + quad * 8;
    const short* X1 = (const short*)Xbf + (size_t)m1 * DIN + quad * 8;
    const short* A0 = (const short*)Abf + (size_t)m0 * DIN + quad * 8;
    const short* A1 = (const short*)Abf + (size_t)m1 * DIN + quad * 8;
    const short* Wl = (const short*)Wpk + lane * 8;

#pragma unroll
    for (int ks = 0; ks < 8; ++ks) {
        short8 bfr[8];
#pragma unroll
        for (int nt = 0; nt < 8; ++nt)
            bfr[nt] = *(const short8*)(Wl + (size_t)(ks * 8 + nt) * 512);
        short8 af0, af1;
        if (ks < 4) {
            af0 = *(const short8*)(X0 + ks * 32);
            af1 = *(const short8*)(X1 + ks * 32);
        } else {
            af0 = *(const short8*)(A0 + (ks - 4) * 32);
            af1 = *(const short8*)(A1 + (ks - 4) * 32);
        }
#pragma unroll
        for (int nt = 0; nt < 8; ++nt) {
            acc[0][nt] = __builtin_amdgcn_mfma_f32_16x16x32_bf16(af0, bfr[nt], acc[0][nt], 0, 0, 0);
            acc[1][nt] = __builtin_amdgcn_mfma_f32_16x16x32_bf16(af1, bfr[nt], acc[1][nt], 0, 0, 0);
        }
    }

    // epilogue: C/D layout col = ln, row = quad*4 + r  (per m-tile)
    float bs[8], we[8];
#pragma unroll
    for (int nt = 0; nt < 8; ++nt) {
        int c = nt * 16 + ln;
        bs[nt] = bself[c];
        we[nt] = wedge[c];
    }
    float psum[8], psq[8];
#pragma unroll
    for (int nt = 0; nt < 8; ++nt) { psum[nt] = 0.0f; psq[nt] = 0.0f; }

#pragma unroll
    for (int mt = 0; mt < 2; ++mt) {
        const int rbase = rowbase + mt * 16 + quad * 4;
        float sv[4];
#pragma unroll
        for (int r = 0; r < 4; ++r) sv[r] = S[rbase + r];
#pragma unroll
        for (int r = 0; r < 4; ++r) {
            float* Hr = H + (size_t)(rbase + r) * DOUT + ln;
#pragma unroll
            for (int nt = 0; nt < 8; ++nt) {
                float h = acc[mt][nt][r] + bs[nt] + sv[r] * we[nt];
                Hr[nt * 16] = h;
                psum[nt] += h;
                psq[nt] += h * h;
            }
        }
    }
    // reduce across quads (lanes ln, ln+16, ln+32, ln+48)
#pragma unroll
    for (int nt = 0; nt < 8; ++nt) {
        psum[nt] += __shfl_down(psum[nt], 32);
        psum[nt] += __shfl_down(psum[nt], 16);
        psq[nt] += __shfl_down(psq[nt], 32);
        psq[nt] += __shfl_down(psq[nt], 16);
    }
    __syncthreads();   // cs/css zeros visible
    if (lane < 16) {
#pragma unroll
        for (int nt = 0; nt < 8; ++nt) {
            atomicAdd(&cs[nt * 16 + ln], psum[nt]);
            atomicAdd(&css[nt * 16 + ln], psq[nt]);
        }
    }
    __syncthreads();
    if (t < 128) {
        atomicAdd(&gsum[t], cs[t]);
        atomicAdd(&gsumsq[t], css[t]);
    }
}

// ---------------------------------------------------------------------------
// 6) normalize + ReLU in place (finalize fused)
// ---------------------------------------------------------------------------
__global__ __launch_bounds__(256) void norm_relu_kernel(
    float* __restrict__ H, const float* __restrict__ gsum,
    const float* __restrict__ gsumsq, const float* __restrict__ gamma,
    const float* __restrict__ beta)
{
    int idx = blockIdx.x * 256 + threadIdx.x;   // over M_*128/4 float4s
    int o4 = (idx & 31) * 4;
    float4 s = *(const float4*)(gsum + o4);
    float4 q = *(const float4*)(gsumsq + o4);
    float4 g = *(const float4*)(gamma + o4);
    float4 bt = *(const float4*)(beta + o4);
    float4 sc, sh;
    {
        float m0 = s.x * NINV, m1 = s.y * NINV, m2 = s.z * NINV, m3 = s.w * NINV;
        float r0 = rsqrtf(q.x * NINV - m0 * m0 + BN_EPS);
        float r1 = rsqrtf(q.y * NINV - m1 * m1 + BN_EPS);
        float r2 = rsqrtf(q.z * NINV - m2 * m2 + BN_EPS);
        float r3 = rsqrtf(q.w * NINV - m3 * m3 + BN_EPS);
        sc.x = g.x * r0; sc.y = g.y * r1; sc.z = g.z * r2; sc.w = g.w * r3;
        sh.x = bt.x - m0 * sc.x; sh.y = bt.y - m1 * sc.y;
        sh.z = bt.z - m2 * sc.z; sh.w = bt.w - m3 * sc.w;
    }
    float4 h = ((const float4*)H)[idx];
    h.x = fmaxf(h.x * sc.x + sh.x, 0.0f);
    h.y = fmaxf(h.y * sc.y + sh.y, 0.0f);
    h.z = fmaxf(h.z * sc.z + sh.z, 0.0f);
    h.w = fmaxf(h.w * sc.w + sh.w, 0.0f);
    ((float4*)H)[idx] = h;
}

// ---------------------------------------------------------------------------
extern "C" void kernel_launch(void* const* d_in, const int* in_sizes, int n_in,
                              void* d_out, int out_size, void* d_ws, size_t ws_size,
                              hipStream_t stream)
{
    const float* X      = (const float*)d_in[0];
    const float* EA     = (const float*)d_in[1];
    const float* Wnode  = (const float*)d_in[2];
    const float* Wedge  = (const float*)d_in[3];
    const float* Wself  = (const float*)d_in[4];
    const float* bself  = (const float*)d_in[5];
    const float* gamma  = (const float*)d_in[6];
    const float* beta   = (const float*)d_in[7];
    const int*   EI     = (const int*)d_in[8];

    int*   wsI    = (int*)d_ws;
    float* wsF    = (float*)d_ws;
    int*   counts = wsI + WS_COUNTS;
    float* gsum   = wsF + WS_SUM;
    float* gsumsq = wsF + WS_SUMSQ;
    int*   rowptr = wsI + WS_ROWPTR;
    int*   cursor = wsI + WS_CURSOR;
    int*   ssrc   = wsI + WS_SSRC;
    int*   seid   = wsI + WS_SEID;
    float* S      = wsF + WS_S;
    unsigned short* Wpk = (unsigned short*)(wsI + WS_WPK);
    unsigned short* Xbf = (unsigned short*)(wsI + WS_XBF);
    unsigned short* Abf = (unsigned short*)(wsI + WS_ABF);
    float* H      = (float*)d_out;

    hipMemsetAsync(d_ws, 0, (size_t)WS_ZERO_UNITS * 4, stream);

    // fused prep: xcvt (10000 blocks) + W pack (16) + hist (625)
    prep_kernel<<<10641, 256, 0, stream>>>(X, Xbf, Wself, Wnode, Wpk, EI, counts);
    scan_kernel<<<1, 256, 0, stream>>>(counts, rowptr, cursor);
    bucket_kernel<<<(E_ + 255) / 256, 256, 0, stream>>>(EI, cursor, ssrc, seid);

    // gather-reduce -> Abf, S  (batch-per-XCD swizzle)
    gather_kernel<<<M_ / 4, 256, 0, stream>>>(Xbf, EA, rowptr, ssrc, seid, Abf, S);

    // MFMA GEMM + stats -> H, gsum, gsumsq (128 rows/block)
    mfma_gemm_kernel<<<M_ / 128, 256, 0, stream>>>(Xbf, Abf, Wpk, S, bself, Wedge,
                                                   H, gsum, gsumsq);

    // normalize + relu (finalize fused)
    norm_relu_kernel<<<(M_ * DOUT / 4) / 256, 256, 0, stream>>>(H, gsum, gsumsq,
                                                                gamma, beta);
}

// Round 6
// 233.338 us; speedup vs baseline: 10.7610x; 1.0101x over previous
//
#include <hip/hip_runtime.h>

// Problem constants
#define B_ 8
#define V_ 10000
#define E_ 160000
#define DIN 128
#define DOUT 128
#define M_ (B_*V_)          // 80000 rows
#define NINV (1.0f/80000.0f)
#define BN_EPS 1e-5f

// Workspace layout (4-byte units):
#define WS_COUNTS  0            // V_            (zeroed)
#define WS_SUM     10000        // 128           (zeroed)
#define WS_SUMSQ   10128        // 128           (zeroed)
#define WS_ROWPTR  10512        // V_+1
#define WS_CURSOR  20513        // V_
#define WS_SSRC    30513        // E_
#define WS_SEID    190513       // E_
#define WS_S       350513       // M_
#define WS_WPK     430516       // 16384 units = 32768 f16 = 64KB (16B aligned)
#define WS_XH      446900       // 5,120,000 units = 10.24M f16
#define WS_AH      5566900      // 5,120,000 units
#define WS_ZERO_UNITS 10256     // counts + gsum + gsumsq

typedef __attribute__((ext_vector_type(2))) _Float16 half2_t;
typedef __attribute__((ext_vector_type(4))) _Float16 half4_t;
typedef __attribute__((ext_vector_type(8))) _Float16 half8_t;
typedef __attribute__((ext_vector_type(4))) float f32x4;

__device__ inline half2_t i2h(unsigned i) {
    half2_t h; __builtin_memcpy(&h, &i, 4); return h;
}
__device__ inline unsigned h2i(half2_t h) {
    unsigned i; __builtin_memcpy(&i, &h, 4); return i;
}

// ---------------------------------------------------------------------------
// 1) fused prep: X->f16 row-major (blocks 0..9999)
//              + W fragment-major f16 pack (blocks 10000..10015)
//              + dst histogram (blocks 10016..10640)
// Wpk layout: for ks in [0,8), nt in [0,8), lane in [0,64):
//   Wpk[((ks*8+nt)*64 + lane)*8 + j] = Wcomb[nt*16 + (lane&15)][ks*32 + (lane>>4)*8 + j]
//   where Wcomb[o][k] = k<128 ? Wself[o][k] : Wnode[o][k-128]
// ---------------------------------------------------------------------------
__global__ __launch_bounds__(256) void prep_kernel(
    const float* __restrict__ X, _Float16* __restrict__ Xh,
    const float* __restrict__ Wself, const float* __restrict__ Wnode,
    _Float16* __restrict__ Wpk,
    const int* __restrict__ EI, int* __restrict__ counts)
{
    const int blk = blockIdx.x;
    const int t = threadIdx.x;
    if (blk < 10000) {
        int idx = blk * 256 + t;                 // over M_*DIN/4
        float4 v = ((const float4*)X)[idx];
        half4_t o = { (_Float16)v.x, (_Float16)v.y, (_Float16)v.z, (_Float16)v.w };
        ((half4_t*)Xh)[idx] = o;
    } else if (blk < 10016) {
        int g = (blk - 10000) * 256 + t;         // 0..4095
        int pair = g >> 6;                       // (ks,nt)
        int lane = g & 63;
        int ks = pair >> 3;
        int nt = pair & 7;
        int o = nt * 16 + (lane & 15);
        int k = ks * 32 + (lane >> 4) * 8;
        const float* wsrc = (k < 128) ? (Wself + o * 128 + k)
                                      : (Wnode + o * 128 + (k - 128));
        _Float16* dst = Wpk + ((size_t)pair * 64 + lane) * 8;
#pragma unroll
        for (int j = 0; j < 8; ++j) dst[j] = (_Float16)wsrc[j];
    } else {
        int e = (blk - 10016) * 256 + t;
        if (e < E_) atomicAdd(&counts[EI[2 * e + 1]], 1);
    }
}

// ---------------------------------------------------------------------------
// 2) exclusive prefix sum over counts -> row_ptr, cursor (single block)
// ---------------------------------------------------------------------------
__global__ __launch_bounds__(256) void scan_kernel(
    const int* __restrict__ counts, int* __restrict__ row_ptr,
    int* __restrict__ cursor)
{
    __shared__ int psum[256];
    const int t = threadIdx.x;
    const int base = t * 40;              // 256*40 = 10240 >= V_
    int local[40];
    int s = 0;
#pragma unroll
    for (int i = 0; i < 40; ++i) {
        int idx = base + i;
        int c = (idx < V_) ? counts[idx] : 0;
        local[i] = s;
        s += c;
    }
    psum[t] = s;
    __syncthreads();
    for (int off = 1; off < 256; off <<= 1) {
        int v = (t >= off) ? psum[t - off] : 0;
        __syncthreads();
        psum[t] += v;
        __syncthreads();
    }
    int excl = (t == 0) ? 0 : psum[t - 1];
#pragma unroll
    for (int i = 0; i < 40; ++i) {
        int idx = base + i;
        if (idx < V_) {
            int rp = excl + local[i];
            row_ptr[idx] = rp;
            cursor[idx] = rp;
        }
    }
    if (t == 255) row_ptr[V_] = psum[255];
}

// ---------------------------------------------------------------------------
// 3) scatter edges into dst-sorted buckets
// ---------------------------------------------------------------------------
__global__ __launch_bounds__(256) void bucket_kernel(
    const int* __restrict__ EI, int* __restrict__ cursor,
    int* __restrict__ ssrc, int* __restrict__ seid)
{
    int e = blockIdx.x * 256 + threadIdx.x;
    if (e < E_) {
        int src = EI[2 * e];
        int dst = EI[2 * e + 1];
        int p = atomicAdd(&cursor[dst], 1);
        ssrc[p] = src;
        seid[p] = e;
    }
}

// ---------------------------------------------------------------------------
// 4) gather-reduce, f16, 2 edges per wave-step, batch-per-XCD swizzled:
//    Ah[b,d,:] = f16( sum_{e:dst=d} Xh[b,src,:] ); S[b,d] = sum ea
//    lanes 0-31 handle even edge of pair, 32-63 odd; 8B (4 halves) per lane.
// ---------------------------------------------------------------------------
__global__ __launch_bounds__(256) void gather_kernel(
    const _Float16* __restrict__ Xh, const float* __restrict__ EA,
    const int* __restrict__ row_ptr, const int* __restrict__ ssrc,
    const int* __restrict__ seid, _Float16* __restrict__ Ah,
    float* __restrict__ S)
{
    const int b = blockIdx.x & 7;             // batch -> XCD
    const int dblk = blockIdx.x >> 3;         // 0..2499
    const int w = threadIdx.x >> 6;           // 4 waves/block
    const int lane = threadIdx.x & 63;
    const int half = lane >> 5;               // which edge of the pair
    const int sl = lane & 31;                 // element group: sl*4 .. sl*4+3
    const int d = dblk * 4 + w;
    const int wid = b * V_ + d;
    const int k0 = row_ptr[d];
    const int k1 = row_ptr[d + 1];
    const _Float16* Xb = Xh + (size_t)b * V_ * DIN + sl * 4;
    const float* EAb = EA + (size_t)b * E_;
    half2_t a0 = (half2_t)0, a1 = (half2_t)0;
    float ea = 0.0f;
    for (int kb = k0; kb < k1; kb += 64) {
        int cnt = min(64, k1 - kb);
        int msrc = 0;
        if (lane < cnt) {
            msrc = ssrc[kb + lane];
            ea += EAb[seid[kb + lane]];
        }
        int j = 0;
        for (; j + 8 <= cnt; j += 8) {
#pragma unroll
            for (int u = 0; u < 4; ++u) {
                int s = __shfl(msrc, j + u * 2 + half);
                uint2 v = *(const uint2*)(Xb + (size_t)s * DIN);
                a0 += i2h(v.x);
                a1 += i2h(v.y);
            }
        }
        for (; j + 2 <= cnt; j += 2) {
            int s = __shfl(msrc, j + half);
            uint2 v = *(const uint2*)(Xb + (size_t)s * DIN);
            a0 += i2h(v.x);
            a1 += i2h(v.y);
        }
        if (j < cnt) {
            int s = __shfl(msrc, j);
            if (half == 0) {
                uint2 v = *(const uint2*)(Xb + (size_t)s * DIN);
                a0 += i2h(v.x);
                a1 += i2h(v.y);
            }
        }
    }
    // combine the two edge-parity halves (lane <- lane+32)
    unsigned c0 = __shfl_down(h2i(a0), 32);
    unsigned c1 = __shfl_down(h2i(a1), 32);
    a0 += i2h(c0);
    a1 += i2h(c1);
    // edge_attr wave reduction
    for (int off = 32; off; off >>= 1) ea += __shfl_down(ea, off);
    if (lane == 0) S[wid] = ea;
    if (half == 0) {
        uint2 o;
        o.x = h2i(a0);
        o.y = h2i(a1);
        *(uint2*)(Ah + (size_t)wid * DIN + sl * 4) = o;
    }
}

// ---------------------------------------------------------------------------
// 5) MFMA GEMM (f16) + fused BN stats.
//    Block = 128 rows x 128 cols, 4 waves; wave = 32 rows (2 m-tiles).
//    B-frags from fragment-packed Wpk: base + lane*16 (fully coalesced).
// ---------------------------------------------------------------------------
__global__ __launch_bounds__(256) void mfma_gemm_kernel(
    const _Float16* __restrict__ Xh, const _Float16* __restrict__ Ah,
    const _Float16* __restrict__ Wpk, const float* __restrict__ S,
    const float* __restrict__ bself, const float* __restrict__ wedge,
    float* __restrict__ H, float* __restrict__ gsum, float* __restrict__ gsumsq)
{
    __shared__ float cs[128];
    __shared__ float css[128];
    const int t = threadIdx.x;
    const int wave = t >> 6;
    const int lane = t & 63;
    const int quad = lane >> 4;
    const int ln = lane & 15;
    const int rowbase = blockIdx.x * 128 + wave * 32;
    const int m0 = rowbase + ln;          // m-tile 0 A-frag row
    const int m1 = rowbase + 16 + ln;     // m-tile 1 A-frag row

    if (t < 128) { cs[t] = 0.0f; css[t] = 0.0f; }

    f32x4 acc[2][8];
#pragma unroll
    for (int mt = 0; mt < 2; ++mt)
#pragma unroll
        for (int nt = 0; nt < 8; ++nt) acc[mt][nt] = (f32x4){0.f, 0.f, 0.f, 0.f};

    const _Float16* X0 = Xh + (size_t)m0 * DIN + quad * 8;
    const _Float16* X1 = Xh + (size_t)m1 * DIN + quad * 8;
    const _Float16* A0 = Ah + (size_t)m0 * DIN + quad * 8;
    const _Float16* A1 = Ah + (size_t)m1 * DIN + quad * 8;
    const _Float16* Wl = Wpk + lane * 8;

#pragma unroll
    for (int ks = 0; ks < 8; ++ks) {
        half8_t bfr[8];
#pragma unroll
        for (int nt = 0; nt < 8; ++nt)
            bfr[nt] = *(const half8_t*)(Wl + (size_t)(ks * 8 + nt) * 512);
        half8_t af0, af1;
        if (ks < 4) {
            af0 = *(const half8_t*)(X0 + ks * 32);
            af1 = *(const half8_t*)(X1 + ks * 32);
        } else {
            af0 = *(const half8_t*)(A0 + (ks - 4) * 32);
            af1 = *(const half8_t*)(A1 + (ks - 4) * 32);
        }
#pragma unroll
        for (int nt = 0; nt < 8; ++nt) {
            acc[0][nt] = __builtin_amdgcn_mfma_f32_16x16x32_f16(af0, bfr[nt], acc[0][nt], 0, 0, 0);
            acc[1][nt] = __builtin_amdgcn_mfma_f32_16x16x32_f16(af1, bfr[nt], acc[1][nt], 0, 0, 0);
        }
    }

    // epilogue: C/D layout col = ln, row = quad*4 + r  (per m-tile)
    float bs[8], we[8];
#pragma unroll
    for (int nt = 0; nt < 8; ++nt) {
        int c = nt * 16 + ln;
        bs[nt] = bself[c];
        we[nt] = wedge[c];
    }
    float psum[8], psq[8];
#pragma unroll
    for (int nt = 0; nt < 8; ++nt) { psum[nt] = 0.0f; psq[nt] = 0.0f; }

#pragma unroll
    for (int mt = 0; mt < 2; ++mt) {
        const int rbase = rowbase + mt * 16 + quad * 4;
        float sv[4];
#pragma unroll
        for (int r = 0; r < 4; ++r) sv[r] = S[rbase + r];
#pragma unroll
        for (int r = 0; r < 4; ++r) {
            float* Hr = H + (size_t)(rbase + r) * DOUT + ln;
#pragma unroll
            for (int nt = 0; nt < 8; ++nt) {
                float h = acc[mt][nt][r] + bs[nt] + sv[r] * we[nt];
                Hr[nt * 16] = h;
                psum[nt] += h;
                psq[nt] += h * h;
            }
        }
    }
    // reduce across quads (lanes ln, ln+16, ln+32, ln+48)
#pragma unroll
    for (int nt = 0; nt < 8; ++nt) {
        psum[nt] += __shfl_down(psum[nt], 32);
        psum[nt] += __shfl_down(psum[nt], 16);
        psq[nt] += __shfl_down(psq[nt], 32);
        psq[nt] += __shfl_down(psq[nt], 16);
    }
    __syncthreads();   // cs/css zeros visible
    if (lane < 16) {
#pragma unroll
        for (int nt = 0; nt < 8; ++nt) {
            atomicAdd(&cs[nt * 16 + ln], psum[nt]);
            atomicAdd(&css[nt * 16 + ln], psq[nt]);
        }
    }
    __syncthreads();
    if (t < 128) {
        atomicAdd(&gsum[t], cs[t]);
        atomicAdd(&gsumsq[t], css[t]);
    }
}

// ---------------------------------------------------------------------------
// 6) normalize + ReLU in place (finalize fused)
// ---------------------------------------------------------------------------
__global__ __launch_bounds__(256) void norm_relu_kernel(
    float* __restrict__ H, const float* __restrict__ gsum,
    const float* __restrict__ gsumsq, const float* __restrict__ gamma,
    const float* __restrict__ beta)
{
    int idx = blockIdx.x * 256 + threadIdx.x;   // over M_*128/4 float4s
    int o4 = (idx & 31) * 4;
    float4 s = *(const float4*)(gsum + o4);
    float4 q = *(const float4*)(gsumsq + o4);
    float4 g = *(const float4*)(gamma + o4);
    float4 bt = *(const float4*)(beta + o4);
    float4 sc, sh;
    {
        float m0 = s.x * NINV, m1 = s.y * NINV, m2 = s.z * NINV, m3 = s.w * NINV;
        float r0 = rsqrtf(q.x * NINV - m0 * m0 + BN_EPS);
        float r1 = rsqrtf(q.y * NINV - m1 * m1 + BN_EPS);
        float r2 = rsqrtf(q.z * NINV - m2 * m2 + BN_EPS);
        float r3 = rsqrtf(q.w * NINV - m3 * m3 + BN_EPS);
        sc.x = g.x * r0; sc.y = g.y * r1; sc.z = g.z * r2; sc.w = g.w * r3;
        sh.x = bt.x - m0 * sc.x; sh.y = bt.y - m1 * sc.y;
        sh.z = bt.z - m2 * sc.z; sh.w = bt.w - m3 * sc.w;
    }
    float4 h = ((const float4*)H)[idx];
    h.x = fmaxf(h.x * sc.x + sh.x, 0.0f);
    h.y = fmaxf(h.y * sc.y + sh.y, 0.0f);
    h.z = fmaxf(h.z * sc.z + sh.z, 0.0f);
    h.w = fmaxf(h.w * sc.w + sh.w, 0.0f);
    ((float4*)H)[idx] = h;
}

// ---------------------------------------------------------------------------
extern "C" void kernel_launch(void* const* d_in, const int* in_sizes, int n_in,
                              void* d_out, int out_size, void* d_ws, size_t ws_size,
                              hipStream_t stream)
{
    const float* X      = (const float*)d_in[0];
    const float* EA     = (const float*)d_in[1];
    const float* Wnode  = (const float*)d_in[2];
    const float* Wedge  = (const float*)d_in[3];
    const float* Wself  = (const float*)d_in[4];
    const float* bself  = (const float*)d_in[5];
    const float* gamma  = (const float*)d_in[6];
    const float* beta   = (const float*)d_in[7];
    const int*   EI     = (const int*)d_in[8];

    int*   wsI    = (int*)d_ws;
    float* wsF    = (float*)d_ws;
    int*   counts = wsI + WS_COUNTS;
    float* gsum   = wsF + WS_SUM;
    float* gsumsq = wsF + WS_SUMSQ;
    int*   rowptr = wsI + WS_ROWPTR;
    int*   cursor = wsI + WS_CURSOR;
    int*   ssrc   = wsI + WS_SSRC;
    int*   seid   = wsI + WS_SEID;
    float* S      = wsF + WS_S;
    _Float16* Wpk = (_Float16*)(wsI + WS_WPK);
    _Float16* Xh  = (_Float16*)(wsI + WS_XH);
    _Float16* Ah  = (_Float16*)(wsI + WS_AH);
    float* H      = (float*)d_out;

    hipMemsetAsync(d_ws, 0, (size_t)WS_ZERO_UNITS * 4, stream);

    // fused prep: xcvt (10000 blocks) + W pack (16) + hist (625)
    prep_kernel<<<10641, 256, 0, stream>>>(X, Xh, Wself, Wnode, Wpk, EI, counts);
    scan_kernel<<<1, 256, 0, stream>>>(counts, rowptr, cursor);
    bucket_kernel<<<(E_ + 255) / 256, 256, 0, stream>>>(EI, cursor, ssrc, seid);

    // gather-reduce -> Ah, S  (batch-per-XCD swizzle, 2 edges/wave-step)
    gather_kernel<<<M_ / 4, 256, 0, stream>>>(Xh, EA, rowptr, ssrc, seid, Ah, S);

    // MFMA GEMM + stats -> H, gsum, gsumsq (128 rows/block)
    mfma_gemm_kernel<<<M_ / 128, 256, 0, stream>>>(Xh, Ah, Wpk, S, bself, Wedge,
                                                   H, gsum, gsumsq);

    // normalize + relu (finalize fused)
    norm_relu_kernel<<<(M_ * DOUT / 4) / 256, 256, 0, stream>>>(H, gsum, gsumsq,
                                                                gamma, beta);
}